// Round 2
// baseline (170.619 us; speedup 1.0000x reference)
//
#include <hip/hip_runtime.h>

#define WAVE   64
#define DLEN   4096
#define EPT    (DLEN / WAVE)   // 64 elements per lane
#define NCHUNK (EPT / 4)       // 16 float4 chunks per lane
#define RPB    4               // rows (waves) per block
#define NITER  30
#define CAP    512             // survivor capacity per row (fallback if exceeded)

__global__ __launch_bounds__(WAVE * RPB, 4)
void entmax_bisect_kernel(const float* __restrict__ scores,
                          const int* __restrict__ mask,
                          const float* __restrict__ alpha_ptr,
                          float* __restrict__ out)
{
    __shared__ float sv[RPB][CAP + WAVE];   // compacted survivors + pad

    const int w    = threadIdx.x >> 6;      // wave id within block = row slot
    const int lane = threadIdx.x & 63;
    const int row  = blockIdx.x * RPB + w;

    const float NEG = -1e30f;

    const float alpha = fmaxf(alpha_ptr[0], 1.001f);
    const float am1   = alpha - 1.0f;
    const float expo  = 1.0f / am1;
    const bool  sq    = (expo == 2.0f);     // alpha == 1.5 exact fast path

    const size_t base = (size_t)row * DLEN;
    const float* srow = scores + base;
    const int*   mrow = mask + base;

    // ---- pass 1: load row into registers, apply mask + scale, row max ----
    float xs[EPT];
    float rmax = NEG;
#pragma unroll
    for (int c = 0; c < NCHUNK; ++c) {
        const int idx = c * (WAVE * 4) + lane * 4;
        const float4 s = *reinterpret_cast<const float4*>(srow + idx);
        const int4   m = *reinterpret_cast<const int4*>(mrow + idx);
        const float x0 = m.x ? s.x * am1 : NEG;
        const float x1 = m.y ? s.y * am1 : NEG;
        const float x2 = m.z ? s.z * am1 : NEG;
        const float x3 = m.w ? s.w * am1 : NEG;
        xs[c*4+0] = x0; xs[c*4+1] = x1; xs[c*4+2] = x2; xs[c*4+3] = x3;
        rmax = fmaxf(rmax, fmaxf(fmaxf(x0, x1), fmaxf(x2, x3)));
    }
#pragma unroll
    for (int off = 32; off; off >>= 1)
        rmax = fmaxf(rmax, __shfl_xor(rmax, off));

    // every tau evaluated by the bisection is >= tau_lo0 = rmax - 1, so
    // elements with x <= tau_lo0 contribute 0 to every sum: compact the rest.
    const float tau_lo0 = rmax - 1.0f;
    const float tau_hi  = rmax - exp2f(-12.0f * am1);  // (1/4096)^(alpha-1) exact

    // ---- stream-compact survivors (x > tau_lo0) into LDS via wave ballot ----
    int cnt = 0;
#pragma unroll
    for (int e = 0; e < EPT; ++e) {
        const bool pred = xs[e] > tau_lo0;
        const unsigned long long bm = __ballot(pred);
        if (pred) {
            const int pos = cnt + __popcll(bm & ((1ull << lane) - 1ull));
            if (pos < CAP) sv[w][pos] = xs[e];
        }
        cnt += __popcll(bm);
    }

    float tau_lo = tau_lo0;
    float tau_m  = tau_lo0;
    float sum_m  = 1.0f;

    if (cnt <= CAP) {
        // -------- fast path: bisection over the compacted LDS list --------
        sv[w][cnt + lane] = NEG;            // pad one full chunk
        const int nc = (cnt + 63) >> 6;

        auto rsum = [&](float tau) -> float {
            float s = 0.f;
            for (int c = 0; c < nc; ++c) {
                const float v = sv[w][c * 64 + lane];
                if (sq) {
                    const float z = fmaxf(v - tau, 0.f);
                    s = fmaf(z, z, s);
                } else {
                    const float z = v - tau;
                    s += (z > 0.f) ? powf(z, expo) : 0.f;
                }
            }
#pragma unroll
            for (int off = 32; off; off >>= 1) s += __shfl_xor(s, off);
            return s;
        };

        const float f_lo = rsum(tau_lo) - 1.0f;
        float dm = tau_hi - tau_lo;
#pragma unroll 1
        for (int it = 0; it < NITER; ++it) {
            dm *= 0.5f;
            tau_m = tau_lo + dm;
            sum_m = rsum(tau_m);
            const float f_m = sum_m - 1.0f;
            tau_lo = (f_m * f_lo >= 0.0f) ? tau_m : tau_lo;
        }
    } else {
        // -------- fallback (never expected on this data): register path --------
        auto rsum = [&](float tau) -> float {
            float s0 = 0.f, s1 = 0.f, s2 = 0.f, s3 = 0.f;
#pragma unroll
            for (int i = 0; i < EPT; i += 4) {
                if (sq) {
                    const float z0 = fmaxf(xs[i+0] - tau, 0.f);
                    const float z1 = fmaxf(xs[i+1] - tau, 0.f);
                    const float z2 = fmaxf(xs[i+2] - tau, 0.f);
                    const float z3 = fmaxf(xs[i+3] - tau, 0.f);
                    s0 = fmaf(z0, z0, s0);
                    s1 = fmaf(z1, z1, s1);
                    s2 = fmaf(z2, z2, s2);
                    s3 = fmaf(z3, z3, s3);
                } else {
                    float z = xs[i+0] - tau; s0 += (z > 0.f) ? powf(z, expo) : 0.f;
                    z = xs[i+1] - tau;       s1 += (z > 0.f) ? powf(z, expo) : 0.f;
                    z = xs[i+2] - tau;       s2 += (z > 0.f) ? powf(z, expo) : 0.f;
                    z = xs[i+3] - tau;       s3 += (z > 0.f) ? powf(z, expo) : 0.f;
                }
            }
            float s = (s0 + s1) + (s2 + s3);
#pragma unroll
            for (int off = 32; off; off >>= 1) s += __shfl_xor(s, off);
            return s;
        };

        const float f_lo = rsum(tau_lo) - 1.0f;
        float dm = tau_hi - tau_lo;
#pragma unroll 1
        for (int it = 0; it < NITER; ++it) {
            dm *= 0.5f;
            tau_m = tau_lo + dm;
            sum_m = rsum(tau_m);
            const float f_m = sum_m - 1.0f;
            tau_lo = (f_m * f_lo >= 0.0f) ? tau_m : tau_lo;
        }
    }

    // ---- epilogue: p = clip(x - tau_m, 0)^exp / sum_m over the full row ----
    const float inv = 1.0f / sum_m;
#pragma unroll
    for (int c = 0; c < NCHUNK; ++c) {
        const int idx = c * (WAVE * 4) + lane * 4;
        float4 o;
        if (sq) {
            float z;
            z = fmaxf(xs[c*4+0] - tau_m, 0.f); o.x = z * z * inv;
            z = fmaxf(xs[c*4+1] - tau_m, 0.f); o.y = z * z * inv;
            z = fmaxf(xs[c*4+2] - tau_m, 0.f); o.z = z * z * inv;
            z = fmaxf(xs[c*4+3] - tau_m, 0.f); o.w = z * z * inv;
        } else {
            float z;
            z = xs[c*4+0] - tau_m; o.x = (z > 0.f) ? powf(z, expo) * inv : 0.f;
            z = xs[c*4+1] - tau_m; o.y = (z > 0.f) ? powf(z, expo) * inv : 0.f;
            z = xs[c*4+2] - tau_m; o.z = (z > 0.f) ? powf(z, expo) * inv : 0.f;
            z = xs[c*4+3] - tau_m; o.w = (z > 0.f) ? powf(z, expo) * inv : 0.f;
        }
        *reinterpret_cast<float4*>(out + base + idx) = o;
    }
}

extern "C" void kernel_launch(void* const* d_in, const int* in_sizes, int n_in,
                              void* d_out, int out_size, void* d_ws, size_t ws_size,
                              hipStream_t stream) {
    const float* scores = (const float*)d_in[0];
    const int*   mask   = (const int*)d_in[1];
    const float* alpha  = (const float*)d_in[2];
    float*       out    = (float*)d_out;
    const int rows = in_sizes[0] / DLEN;
    entmax_bisect_kernel<<<rows / RPB, WAVE * RPB, 0, stream>>>(scores, mask, alpha, out);
}

// Round 3
// 63.137 us; speedup vs baseline: 2.7024x; 2.7024x over previous
//
#include <hip/hip_runtime.h>

#define DLEN    4096
#define TPB     256            // 4 waves per block, one row per block
#define NWAVE   4
#define EPT     16             // elements per lane (4 float4 chunks)
#define NITER   30
#define CAPW    1024           // worst-case survivors per wave (no fallback needed)

__global__ __launch_bounds__(TPB, 4)
void entmax_bisect_kernel(const float* __restrict__ scores,
                          const int* __restrict__ mask,
                          const float* __restrict__ alpha_ptr,
                          float* __restrict__ out)
{
    __shared__ float sv[NWAVE][CAPW + 64];   // per-wave compacted survivors + pad
    __shared__ float part[2][NWAVE];         // double-buffered cross-wave partials
    __shared__ float wred[NWAVE];            // cross-wave max exchange

    const int tid  = threadIdx.x;
    const int w    = tid >> 6;
    const int lane = tid & 63;
    const int row  = blockIdx.x;

    const float NEG = -1e30f;

    const float alpha = fmaxf(alpha_ptr[0], 1.001f);
    const float am1   = alpha - 1.0f;
    const float expo  = 1.0f / am1;
    const bool  sq    = (expo == 2.0f);      // alpha == 1.5 exact fast path

    const size_t base = (size_t)row * DLEN;
    const float* srow = scores + base;
    const int*   mrow = mask + base;

    // ---- load 16 elems/lane into registers, apply mask + scale, row max ----
    float xs[EPT];
    float rmax = NEG;
#pragma unroll
    for (int c = 0; c < 4; ++c) {
        const int idx = c * (TPB * 4) + tid * 4;
        const float4 s = *reinterpret_cast<const float4*>(srow + idx);
        const int4   m = *reinterpret_cast<const int4*>(mrow + idx);
        const float x0 = m.x ? s.x * am1 : NEG;
        const float x1 = m.y ? s.y * am1 : NEG;
        const float x2 = m.z ? s.z * am1 : NEG;
        const float x3 = m.w ? s.w * am1 : NEG;
        xs[c*4+0] = x0; xs[c*4+1] = x1; xs[c*4+2] = x2; xs[c*4+3] = x3;
        rmax = fmaxf(rmax, fmaxf(fmaxf(x0, x1), fmaxf(x2, x3)));
    }
#pragma unroll
    for (int off = 32; off; off >>= 1)
        rmax = fmaxf(rmax, __shfl_xor(rmax, off));
    if (lane == 0) wred[w] = rmax;
    __syncthreads();
    rmax = fmaxf(fmaxf(wred[0], wred[1]), fmaxf(wred[2], wred[3]));

    // every tau evaluated is >= tau_lo0 = rmax - 1: elements below contribute 0
    const float tau_lo0 = rmax - 1.0f;
    const float tau_hi  = rmax - exp2f(-12.0f * am1);   // (1/4096)^(alpha-1), exact

    // ---- per-wave ballot stream-compaction of survivors into LDS ----
    int cnt = 0;
#pragma unroll
    for (int e = 0; e < EPT; ++e) {
        const bool pred = xs[e] > tau_lo0;
        const unsigned long long bm = __ballot(pred);
        if (pred)
            sv[w][cnt + __popcll(bm & ((1ull << lane) - 1ull))] = xs[e];
        cnt += __popcll(bm);
    }
    sv[w][cnt + lane] = NEG;                 // pad one full chunk
    const int nc = (cnt + 63) >> 6;          // chunks this wave scans (usually 1)

    // ---- one row-sum evaluation: wave partial over LDS + cross-wave combine ----
    auto rsum = [&](float tau, int buf) -> float {
        float s = 0.f;
        for (int c = 0; c < nc; ++c) {
            const float v = sv[w][c * 64 + lane];
            if (sq) {
                const float z = fmaxf(v - tau, 0.f);
                s = fmaf(z, z, s);
            } else {
                const float z = v - tau;
                s += (z > 0.f) ? powf(z, expo) : 0.f;
            }
        }
#pragma unroll
        for (int off = 32; off; off >>= 1) s += __shfl_xor(s, off);
        if (lane == 0) part[buf][w] = s;
        __syncthreads();
        const float4 p4 = *reinterpret_cast<const float4*>(part[buf]);
        return (p4.x + p4.y) + (p4.z + p4.w);
    };

    // ---- bisection (all quantities row-uniform after each combine) ----
    float tau_lo = tau_lo0;
    const float f_lo = rsum(tau_lo0, 0) - 1.0f;
    float dm = tau_hi - tau_lo0;
    float tau_m = tau_lo0;
    float sum_m = 1.0f;
#pragma unroll 1
    for (int it = 0; it < NITER; ++it) {
        dm *= 0.5f;
        tau_m = tau_lo + dm;
        sum_m = rsum(tau_m, (it + 1) & 1);
        const float f_m = sum_m - 1.0f;
        tau_lo = (f_m * f_lo >= 0.0f) ? tau_m : tau_lo;
    }

    // ---- epilogue: p = clip(x - tau_m, 0)^exp / sum_m, from registers ----
    const float inv = 1.0f / sum_m;
#pragma unroll
    for (int c = 0; c < 4; ++c) {
        const int idx = c * (TPB * 4) + tid * 4;
        float4 o;
        if (sq) {
            float z;
            z = fmaxf(xs[c*4+0] - tau_m, 0.f); o.x = z * z * inv;
            z = fmaxf(xs[c*4+1] - tau_m, 0.f); o.y = z * z * inv;
            z = fmaxf(xs[c*4+2] - tau_m, 0.f); o.z = z * z * inv;
            z = fmaxf(xs[c*4+3] - tau_m, 0.f); o.w = z * z * inv;
        } else {
            float z;
            z = xs[c*4+0] - tau_m; o.x = (z > 0.f) ? powf(z, expo) * inv : 0.f;
            z = xs[c*4+1] - tau_m; o.y = (z > 0.f) ? powf(z, expo) * inv : 0.f;
            z = xs[c*4+2] - tau_m; o.z = (z > 0.f) ? powf(z, expo) * inv : 0.f;
            z = xs[c*4+3] - tau_m; o.w = (z > 0.f) ? powf(z, expo) * inv : 0.f;
        }
        *reinterpret_cast<float4*>(out + base + idx) = o;
    }
}

extern "C" void kernel_launch(void* const* d_in, const int* in_sizes, int n_in,
                              void* d_out, int out_size, void* d_ws, size_t ws_size,
                              hipStream_t stream) {
    const float* scores = (const float*)d_in[0];
    const int*   mask   = (const int*)d_in[1];
    const float* alpha  = (const float*)d_in[2];
    float*       out    = (float*)d_out;
    const int rows = in_sizes[0] / DLEN;
    entmax_bisect_kernel<<<rows, TPB, 0, stream>>>(scores, mask, alpha, out);
}

// Round 4
// 58.832 us; speedup vs baseline: 2.9001x; 1.0732x over previous
//
#include <hip/hip_runtime.h>

#define DLEN    4096
#define TPB     256            // 4 waves per block, one row per block
#define NWAVE   4
#define EPT     16             // elements per lane (4 float4 chunks)
#define NNEWT   16             // Newton iterations (alpha==1.5 path)
#define NBISECT 31             // bisection evals (general-alpha fallback path)
#define CAPW    1024           // worst-case survivors per wave

__global__ __launch_bounds__(TPB, 8)
void entmax_kernel(const float* __restrict__ scores,
                   const int* __restrict__ mask,
                   const float* __restrict__ alpha_ptr,
                   float* __restrict__ out)
{
    __shared__ float sv[NWAVE][CAPW + 64];   // per-wave compacted survivors + pad
    __shared__ int   wcnt[NWAVE];
    __shared__ float wred[NWAVE];

    const int tid  = threadIdx.x;
    const int w    = tid >> 6;
    const int lane = tid & 63;
    const int row  = blockIdx.x;

    const float NEG = -1e30f;

    const float alpha = fmaxf(alpha_ptr[0], 1.001f);
    const float am1   = alpha - 1.0f;
    const float expo  = 1.0f / am1;
    const bool  sq    = (expo == 2.0f);      // alpha == 1.5 exact fast path

    const size_t base = (size_t)row * DLEN;
    const float* srow = scores + base;
    const int*   mrow = mask + base;

    // ---- load 16 elems/lane into registers, apply mask + scale, row max ----
    float xs[EPT];
    float rmax = NEG;
#pragma unroll
    for (int c = 0; c < 4; ++c) {
        const int idx = c * (TPB * 4) + tid * 4;
        const float4 s = *reinterpret_cast<const float4*>(srow + idx);
        const int4   m = *reinterpret_cast<const int4*>(mrow + idx);
        const float x0 = m.x ? s.x * am1 : NEG;
        const float x1 = m.y ? s.y * am1 : NEG;
        const float x2 = m.z ? s.z * am1 : NEG;
        const float x3 = m.w ? s.w * am1 : NEG;
        xs[c*4+0] = x0; xs[c*4+1] = x1; xs[c*4+2] = x2; xs[c*4+3] = x3;
        rmax = fmaxf(rmax, fmaxf(fmaxf(x0, x1), fmaxf(x2, x3)));
    }
#pragma unroll
    for (int off = 32; off; off >>= 1)
        rmax = fmaxf(rmax, __shfl_xor(rmax, off));
    if (lane == 0) wred[w] = rmax;
    __syncthreads();
    rmax = fmaxf(fmaxf(wred[0], wred[1]), fmaxf(wred[2], wred[3]));

    // every tau ever evaluated is >= tau_lo0 = rmax - 1 (bisection lower bound,
    // and Newton iterates increase from tau_lo0): x <= tau_lo0 contributes 0.
    const float tau_lo0 = rmax - 1.0f;

    // ---- per-wave ballot stream-compaction of survivors into LDS ----
    int cnt = 0;
#pragma unroll
    for (int e = 0; e < EPT; ++e) {
        const bool pred = xs[e] > tau_lo0;
        const unsigned long long bm = __ballot(pred);
        if (pred)
            sv[w][cnt + __popcll(bm & ((1ull << lane) - 1ull))] = xs[e];
        cnt += __popcll(bm);
    }
    sv[w][cnt + lane] = NEG;                 // pad one full chunk
    if (lane == 0) wcnt[w] = cnt;
    __syncthreads();                         // last barrier: sv + wcnt visible to all

    int nct[NWAVE];
#pragma unroll
    for (int ws = 0; ws < NWAVE; ++ws)
        nct[ws] = (wcnt[ws] + 63) >> 6;      // chunks per segment (usually 1)

    float tau_m = tau_lo0;
    float sum_m = 1.0f;

    if (sq) {
        // ---- Newton, redundant per wave over all 4 LDS segments, no barriers ----
#pragma unroll 1
        for (int it = 0; it < NNEWT; ++it) {
            float s2 = 0.f, s1 = 0.f;
            for (int ws = 0; ws < NWAVE; ++ws) {
                const int n = nct[ws];
                for (int c = 0; c < n; ++c) {
                    const float z = fmaxf(sv[ws][c * 64 + lane] - tau_m, 0.f);
                    s2 = fmaf(z, z, s2);
                    s1 += z;
                }
            }
#pragma unroll
            for (int off = 32; off; off >>= 1) {
                s2 += __shfl_xor(s2, off);
                s1 += __shfl_xor(s1, off);
            }
            sum_m = s2;
            if (it < NNEWT - 1 && s1 > 0.f)
                tau_m += (s2 - 1.0f) * 0.5f / s1;   // convex f: monotone from below
        }
    } else {
        // ---- general alpha: reference-faithful bisection, redundant scan ----
        const float tau_hi = rmax - exp2f(-12.0f * am1);  // (1/4096)^(alpha-1)

        auto rsum = [&](float tau) -> float {
            float s = 0.f;
            for (int ws = 0; ws < NWAVE; ++ws) {
                const int n = nct[ws];
                for (int c = 0; c < n; ++c) {
                    const float z = sv[ws][c * 64 + lane] - tau;
                    s += (z > 0.f) ? powf(z, expo) : 0.f;
                }
            }
#pragma unroll
            for (int off = 32; off; off >>= 1) s += __shfl_xor(s, off);
            return s;
        };

        float tau_lo = tau_lo0;
        const float f_lo = rsum(tau_lo0) - 1.0f;
        float dm = tau_hi - tau_lo0;
#pragma unroll 1
        for (int it = 0; it < NBISECT; ++it) {
            dm *= 0.5f;
            tau_m = tau_lo + dm;
            sum_m = rsum(tau_m);
            const float f_m = sum_m - 1.0f;
            tau_lo = (f_m * f_lo >= 0.0f) ? tau_m : tau_lo;
        }
    }

    // ---- epilogue: p = clip(x - tau_m, 0)^exp / sum_m, from registers ----
    const float inv = 1.0f / sum_m;
#pragma unroll
    for (int c = 0; c < 4; ++c) {
        const int idx = c * (TPB * 4) + tid * 4;
        float4 o;
        if (sq) {
            float z;
            z = fmaxf(xs[c*4+0] - tau_m, 0.f); o.x = z * z * inv;
            z = fmaxf(xs[c*4+1] - tau_m, 0.f); o.y = z * z * inv;
            z = fmaxf(xs[c*4+2] - tau_m, 0.f); o.z = z * z * inv;
            z = fmaxf(xs[c*4+3] - tau_m, 0.f); o.w = z * z * inv;
        } else {
            float z;
            z = xs[c*4+0] - tau_m; o.x = (z > 0.f) ? powf(z, expo) * inv : 0.f;
            z = xs[c*4+1] - tau_m; o.y = (z > 0.f) ? powf(z, expo) * inv : 0.f;
            z = xs[c*4+2] - tau_m; o.z = (z > 0.f) ? powf(z, expo) * inv : 0.f;
            z = xs[c*4+3] - tau_m; o.w = (z > 0.f) ? powf(z, expo) * inv : 0.f;
        }
        *reinterpret_cast<float4*>(out + base + idx) = o;
    }
}

extern "C" void kernel_launch(void* const* d_in, const int* in_sizes, int n_in,
                              void* d_out, int out_size, void* d_ws, size_t ws_size,
                              hipStream_t stream) {
    const float* scores = (const float*)d_in[0];
    const int*   mask   = (const int*)d_in[1];
    const float* alpha  = (const float*)d_in[2];
    float*       out    = (float*)d_out;
    const int rows = in_sizes[0] / DLEN;
    entmax_kernel<<<rows, TPB, 0, stream>>>(scores, mask, alpha, out);
}

// Round 5
// 38.969 us; speedup vs baseline: 4.3783x; 1.5097x over previous
//
#include <hip/hip_runtime.h>

#define DLEN     4096
#define TPB      256           // 4 waves per block, one row per block
#define NWAVE    4
#define EPT      16            // elements per lane (4 float4 chunks)
#define CAPW     1024          // worst-case survivors per wave
#define NEWT_MAX 12            // Newton cap, fast path (typical exit ~5-6)
#define NEWT_MAXG 30           // Newton cap, general LDS path
#define NBISECT  31            // bisection evals (general-alpha path)
#define FEPS     1e-6f

__device__ __forceinline__ int prefix_cnt(unsigned long long bm) {
    // popcount of bm over lanes strictly below this lane
    return __builtin_amdgcn_mbcnt_hi((unsigned)(bm >> 32),
           __builtin_amdgcn_mbcnt_lo((unsigned)bm, 0u));
}

__global__ __launch_bounds__(TPB, 8)
void entmax_kernel(const float* __restrict__ scores,
                   const int* __restrict__ mask,
                   const float* __restrict__ alpha_ptr,
                   float* __restrict__ out)
{
    __shared__ float sv[NWAVE][CAPW + 64];   // per-wave compacted survivors + pad
    __shared__ int   wcnt[NWAVE];
    __shared__ float wred[NWAVE];

    const int tid  = threadIdx.x;
    const int w    = tid >> 6;
    const int lane = tid & 63;
    const int row  = blockIdx.x;

    const float NEG = -1e30f;

    const float alpha = fmaxf(alpha_ptr[0], 1.001f);
    const float am1   = alpha - 1.0f;
    const float expo  = 1.0f / am1;
    const bool  sq    = (expo == 2.0f);      // alpha == 1.5 exact fast path

    const size_t base = (size_t)row * DLEN;
    const float* srow = scores + base;
    const int*   mrow = mask + base;

    // ---- load 16 elems/lane into registers, apply mask + scale, row max ----
    float xs[EPT];
    float rmax = NEG;
#pragma unroll
    for (int c = 0; c < 4; ++c) {
        const int idx = c * (TPB * 4) + tid * 4;
        const float4 s = *reinterpret_cast<const float4*>(srow + idx);
        const int4   m = *reinterpret_cast<const int4*>(mrow + idx);
        const float x0 = m.x ? s.x * am1 : NEG;
        const float x1 = m.y ? s.y * am1 : NEG;
        const float x2 = m.z ? s.z * am1 : NEG;
        const float x3 = m.w ? s.w * am1 : NEG;
        xs[c*4+0] = x0; xs[c*4+1] = x1; xs[c*4+2] = x2; xs[c*4+3] = x3;
        rmax = fmaxf(rmax, fmaxf(fmaxf(x0, x1), fmaxf(x2, x3)));
    }
#pragma unroll
    for (int off = 32; off; off >>= 1)
        rmax = fmaxf(rmax, __shfl_xor(rmax, off));
    if (lane == 0) wred[w] = rmax;
    __syncthreads();
    rmax = fmaxf(fmaxf(wred[0], wred[1]), fmaxf(wred[2], wred[3]));

    // every tau ever evaluated is >= tau_lo0 = rmax - 1 (bisection lower bound;
    // Newton from below only increases): x <= tau_lo0 contributes 0 always.
    const float tau_lo0 = rmax - 1.0f;

    // ---- per-wave ballot stream-compaction of survivors into LDS ----
    int cnt = 0;
#pragma unroll
    for (int e = 0; e < EPT; ++e) {
        const bool pred = xs[e] > tau_lo0;
        const unsigned long long bm = __ballot(pred);
        if (pred)
            sv[w][cnt + prefix_cnt(bm)] = xs[e];
        cnt += __popcll(bm);
    }
    sv[w][cnt + lane] = NEG;                 // pad one full chunk
    if (lane == 0) wcnt[w] = cnt;
    __syncthreads();                         // sv + wcnt visible to all waves

    int nct[NWAVE];
    bool fast = true;
#pragma unroll
    for (int ws = 0; ws < NWAVE; ++ws) {
        const int c4 = wcnt[ws];
        nct[ws] = (c4 + 63) >> 6;
        fast = fast && (c4 <= 64);
    }

    float tau_m = tau_lo0;
    float sum_m = 0.0f;

    if (sq) {
        if (fast) {
            // ---- hot path: <=64 survivors/wave -> 4 register values/lane,
            //      Newton with no LDS traffic, wave-uniform early exit ----
            const float r0 = sv[0][lane];
            const float r1 = sv[1][lane];
            const float r2 = sv[2][lane];
            const float r3 = sv[3][lane];
#pragma unroll 1
            for (int it = 0; it < NEWT_MAX; ++it) {
                const float z0 = fmaxf(r0 - tau_m, 0.f);
                const float z1 = fmaxf(r1 - tau_m, 0.f);
                const float z2 = fmaxf(r2 - tau_m, 0.f);
                const float z3 = fmaxf(r3 - tau_m, 0.f);
                float s2 = z0 * z0;
                s2 = fmaf(z1, z1, s2);
                s2 = fmaf(z2, z2, s2);
                s2 = fmaf(z3, z3, s2);
                float s1 = (z0 + z1) + (z2 + z3);
#pragma unroll
                for (int off = 32; off; off >>= 1) {
                    s2 += __shfl_xor(s2, off);
                    s1 += __shfl_xor(s1, off);
                }
                sum_m = s2;
                const float f = s2 - 1.0f;
                if (!(f > FEPS) || !(s1 > 0.f)) break;     // converged from below
                if (it < NEWT_MAX - 1)
                    tau_m += f * 0.5f / s1;                // keep (tau,sum) consistent
            }
        } else {
            // ---- general survivor count: Newton over LDS segments ----
#pragma unroll 1
            for (int it = 0; it < NEWT_MAXG; ++it) {
                float s2 = 0.f, s1 = 0.f;
                for (int ws = 0; ws < NWAVE; ++ws) {
                    const int n = nct[ws];
                    for (int c = 0; c < n; ++c) {
                        const float z = fmaxf(sv[ws][c * 64 + lane] - tau_m, 0.f);
                        s2 = fmaf(z, z, s2);
                        s1 += z;
                    }
                }
#pragma unroll
                for (int off = 32; off; off >>= 1) {
                    s2 += __shfl_xor(s2, off);
                    s1 += __shfl_xor(s1, off);
                }
                sum_m = s2;
                const float f = s2 - 1.0f;
                if (!(f > FEPS) || !(s1 > 0.f)) break;
                if (it < NEWT_MAXG - 1)
                    tau_m += f * 0.5f / s1;
            }
        }
    } else {
        // ---- general alpha: reference-faithful bisection, redundant scan ----
        const float tau_hi = rmax - exp2f(-12.0f * am1);  // (1/4096)^(alpha-1)

        auto rsum = [&](float tau) -> float {
            float s = 0.f;
            for (int ws = 0; ws < NWAVE; ++ws) {
                const int n = nct[ws];
                for (int c = 0; c < n; ++c) {
                    const float z = sv[ws][c * 64 + lane] - tau;
                    s += (z > 0.f) ? powf(z, expo) : 0.f;
                }
            }
#pragma unroll
            for (int off = 32; off; off >>= 1) s += __shfl_xor(s, off);
            return s;
        };

        float tau_lo = tau_lo0;
        const float f_lo = rsum(tau_lo0) - 1.0f;
        float dm = tau_hi - tau_lo0;
#pragma unroll 1
        for (int it = 0; it < NBISECT; ++it) {
            dm *= 0.5f;
            tau_m = tau_lo + dm;
            sum_m = rsum(tau_m);
            const float f_m = sum_m - 1.0f;
            tau_lo = (f_m * f_lo >= 0.0f) ? tau_m : tau_lo;
        }
    }

    // ---- epilogue: p = clip(x - tau_m, 0)^exp / sum_m, from registers ----
    const float inv = 1.0f / sum_m;
#pragma unroll
    for (int c = 0; c < 4; ++c) {
        const int idx = c * (TPB * 4) + tid * 4;
        float4 o;
        if (sq) {
            float z;
            z = fmaxf(xs[c*4+0] - tau_m, 0.f); o.x = z * z * inv;
            z = fmaxf(xs[c*4+1] - tau_m, 0.f); o.y = z * z * inv;
            z = fmaxf(xs[c*4+2] - tau_m, 0.f); o.z = z * z * inv;
            z = fmaxf(xs[c*4+3] - tau_m, 0.f); o.w = z * z * inv;
        } else {
            float z;
            z = xs[c*4+0] - tau_m; o.x = (z > 0.f) ? powf(z, expo) * inv : 0.f;
            z = xs[c*4+1] - tau_m; o.y = (z > 0.f) ? powf(z, expo) * inv : 0.f;
            z = xs[c*4+2] - tau_m; o.z = (z > 0.f) ? powf(z, expo) * inv : 0.f;
            z = xs[c*4+3] - tau_m; o.w = (z > 0.f) ? powf(z, expo) * inv : 0.f;
        }
        *reinterpret_cast<float4*>(out + base + idx) = o;
    }
}

extern "C" void kernel_launch(void* const* d_in, const int* in_sizes, int n_in,
                              void* d_out, int out_size, void* d_ws, size_t ws_size,
                              hipStream_t stream) {
    const float* scores = (const float*)d_in[0];
    const int*   mask   = (const int*)d_in[1];
    const float* alpha  = (const float*)d_in[2];
    float*       out    = (float*)d_out;
    const int rows = in_sizes[0] / DLEN;
    entmax_kernel<<<rows, TPB, 0, stream>>>(scores, mask, alpha, out);
}

// Round 7
// 38.576 us; speedup vs baseline: 4.4229x; 1.0102x over previous
//
#include <hip/hip_runtime.h>

#define DLEN     4096
#define TPB      256           // 4 waves per block, one row per block
#define NWAVE    4
#define EPT      16            // elements per lane (4 float4 chunks)
#define CAPW     1024          // worst-case survivors per wave
#define NEWT_MAX 12            // Newton cap, fast path (typical exit ~5-6)
#define NEWT_MAXG 30           // Newton cap, general LDS path
#define NBISECT  31            // bisection evals (general-alpha path)
#define FEPS     1e-6f

typedef float floatx4 __attribute__((ext_vector_type(4)));  // native vec for nt-store

__device__ __forceinline__ int prefix_cnt(unsigned long long bm) {
    // popcount of bm over lanes strictly below this lane
    return __builtin_amdgcn_mbcnt_hi((unsigned)(bm >> 32),
           __builtin_amdgcn_mbcnt_lo((unsigned)bm, 0u));
}

__global__ __launch_bounds__(TPB, 8)
void entmax_kernel(const float* __restrict__ scores,
                   const int* __restrict__ mask,
                   const float* __restrict__ alpha_ptr,
                   float* __restrict__ out)
{
    __shared__ float sv[NWAVE][CAPW + 64];   // per-wave compacted survivors + pad
    __shared__ int   wcnt[NWAVE];
    __shared__ float wred[NWAVE];

    const int tid  = threadIdx.x;
    const int w    = tid >> 6;
    const int lane = tid & 63;
    const int row  = blockIdx.x;

    const float NEG = -1e30f;

    const float alpha = fmaxf(alpha_ptr[0], 1.001f);
    const float am1   = alpha - 1.0f;
    const float expo  = 1.0f / am1;
    const bool  sq    = (expo == 2.0f);      // alpha == 1.5 exact fast path

    const size_t base = (size_t)row * DLEN;
    const float* srow = scores + base;
    const int*   mrow = mask + base;

    // ---- load 16 elems/lane into registers, apply mask + scale, wave max ----
    float xs[EPT];
    float wmax = NEG;
#pragma unroll
    for (int c = 0; c < 4; ++c) {
        const int idx = c * (TPB * 4) + tid * 4;
        const float4 s = *reinterpret_cast<const float4*>(srow + idx);
        const int4   m = *reinterpret_cast<const int4*>(mrow + idx);
        const float x0 = m.x ? s.x * am1 : NEG;
        const float x1 = m.y ? s.y * am1 : NEG;
        const float x2 = m.z ? s.z * am1 : NEG;
        const float x3 = m.w ? s.w * am1 : NEG;
        xs[c*4+0] = x0; xs[c*4+1] = x1; xs[c*4+2] = x2; xs[c*4+3] = x3;
        wmax = fmaxf(wmax, fmaxf(fmaxf(x0, x1), fmaxf(x2, x3)));
    }
#pragma unroll
    for (int off = 32; off; off >>= 1)
        wmax = fmaxf(wmax, __shfl_xor(wmax, off));

    // Compact on the WAVE-local threshold wmax-1 <= rmax-1 = tau_lo0:
    // superset of true survivors (extras contribute exactly 0 at any
    // evaluated tau >= tau_lo0). Lets compaction run before any barrier.
    const float thr = wmax - 1.0f;
    int cnt = 0;
#pragma unroll
    for (int e = 0; e < EPT; ++e) {
        const bool pred = xs[e] > thr;
        const unsigned long long bm = __ballot(pred);
        if (pred)
            sv[w][cnt + prefix_cnt(bm)] = xs[e];
        cnt += __popcll(bm);
    }
    sv[w][cnt + lane] = NEG;                 // pad one full chunk
    if (lane == 0) { wcnt[w] = cnt; wred[w] = wmax; }
    __syncthreads();                         // single barrier: sv/wcnt/wred visible

    const float rmax = fmaxf(fmaxf(wred[0], wred[1]), fmaxf(wred[2], wred[3]));
    // every tau ever evaluated is >= tau_lo0 = rmax - 1 (bisection lower bound;
    // Newton from below only increases).
    const float tau_lo0 = rmax - 1.0f;

    int nct[NWAVE];
    bool fast = true;
#pragma unroll
    for (int ws = 0; ws < NWAVE; ++ws) {
        const int c4 = wcnt[ws];
        nct[ws] = (c4 + 63) >> 6;
        fast = fast && (c4 <= 64);
    }

    float tau_m = tau_lo0;
    float sum_m = 0.0f;

    if (sq) {
        if (fast) {
            // ---- hot path: <=64 survivors/wave -> 4 register values/lane,
            //      Newton with no LDS traffic, wave-uniform early exit ----
            const float r0 = sv[0][lane];
            const float r1 = sv[1][lane];
            const float r2 = sv[2][lane];
            const float r3 = sv[3][lane];
#pragma unroll 1
            for (int it = 0; it < NEWT_MAX; ++it) {
                const float z0 = fmaxf(r0 - tau_m, 0.f);
                const float z1 = fmaxf(r1 - tau_m, 0.f);
                const float z2 = fmaxf(r2 - tau_m, 0.f);
                const float z3 = fmaxf(r3 - tau_m, 0.f);
                float s2 = z0 * z0;
                s2 = fmaf(z1, z1, s2);
                s2 = fmaf(z2, z2, s2);
                s2 = fmaf(z3, z3, s2);
                float s1 = (z0 + z1) + (z2 + z3);
#pragma unroll
                for (int off = 32; off; off >>= 1) {
                    s2 += __shfl_xor(s2, off);
                    s1 += __shfl_xor(s1, off);
                }
                sum_m = s2;
                const float f = s2 - 1.0f;
                if (!(f > FEPS) || !(s1 > 0.f)) break;     // converged from below
                if (it < NEWT_MAX - 1)
                    tau_m += f * 0.5f / s1;                // keep (tau,sum) consistent
            }
        } else {
            // ---- general survivor count: Newton over LDS segments ----
#pragma unroll 1
            for (int it = 0; it < NEWT_MAXG; ++it) {
                float s2 = 0.f, s1 = 0.f;
                for (int ws = 0; ws < NWAVE; ++ws) {
                    const int n = nct[ws];
                    for (int c = 0; c < n; ++c) {
                        const float z = fmaxf(sv[ws][c * 64 + lane] - tau_m, 0.f);
                        s2 = fmaf(z, z, s2);
                        s1 += z;
                    }
                }
#pragma unroll
                for (int off = 32; off; off >>= 1) {
                    s2 += __shfl_xor(s2, off);
                    s1 += __shfl_xor(s1, off);
                }
                sum_m = s2;
                const float f = s2 - 1.0f;
                if (!(f > FEPS) || !(s1 > 0.f)) break;
                if (it < NEWT_MAXG - 1)
                    tau_m += f * 0.5f / s1;
            }
        }
    } else {
        // ---- general alpha: reference-faithful bisection, redundant scan ----
        const float tau_hi = rmax - exp2f(-12.0f * am1);  // (1/4096)^(alpha-1)

        auto rsum = [&](float tau) -> float {
            float s = 0.f;
            for (int ws = 0; ws < NWAVE; ++ws) {
                const int n = nct[ws];
                for (int c = 0; c < n; ++c) {
                    const float z = sv[ws][c * 64 + lane] - tau;
                    s += (z > 0.f) ? powf(z, expo) : 0.f;
                }
            }
#pragma unroll
            for (int off = 32; off; off >>= 1) s += __shfl_xor(s, off);
            return s;
        };

        float tau_lo = tau_lo0;
        const float f_lo = rsum(tau_lo0) - 1.0f;
        float dm = tau_hi - tau_lo0;
#pragma unroll 1
        for (int it = 0; it < NBISECT; ++it) {
            dm *= 0.5f;
            tau_m = tau_lo + dm;
            sum_m = rsum(tau_m);
            const float f_m = sum_m - 1.0f;
            tau_lo = (f_m * f_lo >= 0.0f) ? tau_m : tau_lo;
        }
    }

    // ---- epilogue: p = clip(x - tau_m, 0)^exp / sum_m, from registers.
    //      Output is write-once, never re-read: nontemporal stores keep it
    //      from evicting the L3-resident inputs between graph replays. ----
    const float inv = 1.0f / sum_m;
#pragma unroll
    for (int c = 0; c < 4; ++c) {
        const int idx = c * (TPB * 4) + tid * 4;
        floatx4 o;
        if (sq) {
            float z;
            z = fmaxf(xs[c*4+0] - tau_m, 0.f); o.x = z * z * inv;
            z = fmaxf(xs[c*4+1] - tau_m, 0.f); o.y = z * z * inv;
            z = fmaxf(xs[c*4+2] - tau_m, 0.f); o.z = z * z * inv;
            z = fmaxf(xs[c*4+3] - tau_m, 0.f); o.w = z * z * inv;
        } else {
            float z;
            z = xs[c*4+0] - tau_m; o.x = (z > 0.f) ? powf(z, expo) * inv : 0.f;
            z = xs[c*4+1] - tau_m; o.y = (z > 0.f) ? powf(z, expo) * inv : 0.f;
            z = xs[c*4+2] - tau_m; o.z = (z > 0.f) ? powf(z, expo) * inv : 0.f;
            z = xs[c*4+3] - tau_m; o.w = (z > 0.f) ? powf(z, expo) * inv : 0.f;
        }
        __builtin_nontemporal_store(o, reinterpret_cast<floatx4*>(out + base + idx));
    }
}

extern "C" void kernel_launch(void* const* d_in, const int* in_sizes, int n_in,
                              void* d_out, int out_size, void* d_ws, size_t ws_size,
                              hipStream_t stream) {
    const float* scores = (const float*)d_in[0];
    const int*   mask   = (const int*)d_in[1];
    const float* alpha  = (const float*)d_in[2];
    float*       out    = (float*)d_out;
    const int rows = in_sizes[0] / DLEN;
    entmax_kernel<<<rows, TPB, 0, stream>>>(scores, mask, alpha, out);
}